// Round 1
// baseline (477.123 us; speedup 1.0000x reference)
//
#include <hip/hip_runtime.h>

// LengthRegulator: out[b,d,m] = sum_n x[b,d,n] * path[b,n,m]
// path is one-hot along n (monotone alignment), so this is a gather:
//   out[b,d,m] = x[b, d, idx[b,m]] * path[b, idx[b,m], m]
// We find the nonzero per mel-column (phase 1, per-wave early exit since idx
// is sorted along m -> whole wave's hits live in a narrow row window), then
// broadcast-gather x and stream the output (phase 2).

#define BATCH   32
#define DIM     384
#define T_TEXT  512
#define T_MEL   4096
#define MTILE   256   // mel columns per block == blockDim.x

__global__ __launch_bounds__(MTILE) void length_regulator_kernel(
    const float* __restrict__ x,      // [B, D, T_TEXT]
    const float* __restrict__ path,   // [B, T_TEXT, T_MEL]
    float* __restrict__ out)          // [B, D, T_MEL]
{
    const int mt = blockIdx.x;            // mel tile 0..15
    const int b  = blockIdx.y;            // batch
    const int t  = threadIdx.x;           // 0..255
    const int m  = mt * MTILE + t;        // this thread's mel column

    // ---- Phase 1: locate the one-hot row for column m --------------------
    // Lane-coalesced: per n, the 64 lanes of a wave read 256 contiguous bytes.
    const float* pcol = path + (size_t)b * T_TEXT * T_MEL + m;
    int   idx   = 0;
    float scale = 0.0f;
    bool  found = false;
    for (int n = 0; n < T_TEXT; n += 4) {
        // 4 outstanding loads per lane for latency hiding
        float v0 = pcol[(size_t)(n + 0) * T_MEL];
        float v1 = pcol[(size_t)(n + 1) * T_MEL];
        float v2 = pcol[(size_t)(n + 2) * T_MEL];
        float v3 = pcol[(size_t)(n + 3) * T_MEL];
        if (v0 != 0.0f) { idx = n + 0; scale = v0; found = true; }
        if (v1 != 0.0f) { idx = n + 1; scale = v1; found = true; }
        if (v2 != 0.0f) { idx = n + 2; scale = v2; found = true; }
        if (v3 != 0.0f) { idx = n + 3; scale = v3; found = true; }
        // idx is sorted along m, so a wave's 64 hits cluster in a few rows:
        // once every lane has found its 1, stop reading path.
        if (__all(found)) break;
    }

    // ---- Phase 2: out[b,d,m] = x[b,d,idx] * scale for all d --------------
    // Gather reads hit the same few cache lines across the wave (idx spans
    // ~8 values per 64 lanes); stores are fully coalesced (256 B/wave/instr).
    const float* xb = x + (size_t)b * DIM * T_TEXT + idx;
    float*       ob = out + (size_t)b * DIM * T_MEL + m;
    #pragma unroll 4
    for (int d = 0; d < DIM; ++d) {
        ob[(size_t)d * T_MEL] = xb[(size_t)d * T_TEXT] * scale;
    }
}

extern "C" void kernel_launch(void* const* d_in, const int* in_sizes, int n_in,
                              void* d_out, int out_size, void* d_ws, size_t ws_size,
                              hipStream_t stream) {
    (void)in_sizes; (void)n_in; (void)d_ws; (void)ws_size; (void)out_size;
    const float* x    = (const float*)d_in[0];   // [32, 384, 512]
    const float* path = (const float*)d_in[1];   // [32, 512, 4096]
    float*       out  = (float*)d_out;           // [32, 384, 4096]

    dim3 grid(T_MEL / MTILE, BATCH);             // (16, 32) = 512 blocks
    dim3 block(MTILE);                           // 256 threads
    length_regulator_kernel<<<grid, block, 0, stream>>>(x, path, out);
}

// Round 2
// 385.108 us; speedup vs baseline: 1.2389x; 1.2389x over previous
//
#include <hip/hip_runtime.h>

// LengthRegulator: out[b,d,m] = x[b, d, idx[b,m]] * path[b, idx[b,m], m]
// (path is one-hot along the text axis, idx sorted along m).
//
// Two-kernel plan:
//  K1: per mel column, find the one-hot row. idx[m] is the m-th order
//      statistic of 4096 uniforms over [0,512) => idx[m] ~ m/8 +- ~15, so we
//      start the scan at wave-uniform (m/8 - 56) and fall back to [0,start)
//      if not found (correct for arbitrary input). Writes idx+scale to ws.
//  K2: one block per (b,d) row: stage the 2 KB x-row in LDS, then stream the
//      4096-wide output row with float4 stores. 12288 blocks => full
//      occupancy, write-BW-bound.

#define BATCH   32
#define DIM     384
#define T_TEXT  512
#define T_MEL   4096

__global__ __launch_bounds__(256) void find_idx_kernel(
    const float* __restrict__ path,    // [B, T_TEXT, T_MEL]
    int*   __restrict__ idx_ws,        // [B, T_MEL]
    float* __restrict__ scale_ws)      // [B, T_MEL]
{
    const int b = blockIdx.y;
    const int m = blockIdx.x * 256 + threadIdx.x;
    const float* pcol = path + (size_t)b * T_TEXT * T_MEL + m;

    // Wave-uniform starting row: expected idx ~= m/8, slack 56 rows (>10 sigma).
    // (m & ~63)/8 is a multiple of 8, so groups of 8 tile [start, 512) exactly.
    int start = (m & ~63) / 8 - 56;
    if (start < 0) start = 0;

    int   idx   = 0;
    float scale = 0.0f;
    bool  found = false;

    for (int n = start; n < T_TEXT; n += 8) {
        float v[8];
        #pragma unroll
        for (int j = 0; j < 8; ++j) v[j] = pcol[(size_t)(n + j) * T_MEL];
        #pragma unroll
        for (int j = 0; j < 8; ++j)
            if (v[j] != 0.0f) { idx = n + j; scale = v[j]; found = true; }
        if (__all(found)) break;   // idx sorted => wave's hits cluster
    }
    if (!__all(found)) {           // guaranteed-correct fallback (rarely taken)
        for (int n = 0; n < start; n += 8) {
            float v[8];
            #pragma unroll
            for (int j = 0; j < 8; ++j) v[j] = pcol[(size_t)(n + j) * T_MEL];
            #pragma unroll
            for (int j = 0; j < 8; ++j)
                if (!found && v[j] != 0.0f) { idx = n + j; scale = v[j]; found = true; }
            if (__all(found)) break;
        }
    }
    idx_ws[b * T_MEL + m]   = idx;
    scale_ws[b * T_MEL + m] = scale;
}

__global__ __launch_bounds__(256) void gather_kernel(
    const float* __restrict__ x,        // [B, D, T_TEXT]
    const int*   __restrict__ idx_ws,   // [B, T_MEL]
    const float* __restrict__ scale_ws, // [B, T_MEL]
    float* __restrict__ out)            // [B, D, T_MEL]
{
    const int d = blockIdx.x;
    const int b = blockIdx.y;
    const int t = threadIdx.x;

    __shared__ float xs[T_TEXT];
    const float* xr = x + ((size_t)b * DIM + d) * T_TEXT;
    xs[t]       = xr[t];
    xs[t + 256] = xr[t + 256];
    __syncthreads();

    const int*   ip = idx_ws   + b * T_MEL;
    const float* sp = scale_ws + b * T_MEL;
    float* orow = out + ((size_t)b * DIM + d) * T_MEL;

    #pragma unroll
    for (int mt = 0; mt < 4; ++mt) {
        const int m4 = mt * 1024 + t * 4;
        const int4   i4 = *(const int4*)  (ip + m4);
        const float4 s4 = *(const float4*)(sp + m4);
        float4 o;
        o.x = xs[i4.x] * s4.x;   // idx clusters across lanes -> LDS broadcast
        o.y = xs[i4.y] * s4.y;
        o.z = xs[i4.z] * s4.z;
        o.w = xs[i4.w] * s4.w;
        *(float4*)(orow + m4) = o;   // 16 B/lane coalesced store
    }
}

extern "C" void kernel_launch(void* const* d_in, const int* in_sizes, int n_in,
                              void* d_out, int out_size, void* d_ws, size_t ws_size,
                              hipStream_t stream) {
    (void)in_sizes; (void)n_in; (void)ws_size; (void)out_size;
    const float* x    = (const float*)d_in[0];   // [32, 384, 512]
    const float* path = (const float*)d_in[1];   // [32, 512, 4096]
    float*       out  = (float*)d_out;           // [32, 384, 4096]

    int*   idx_ws   = (int*)d_ws;                          // 512 KB
    float* scale_ws = (float*)((char*)d_ws + (size_t)BATCH * T_MEL * sizeof(int));

    dim3 g1(T_MEL / 256, BATCH);      // 512 blocks
    find_idx_kernel<<<g1, dim3(256), 0, stream>>>(path, idx_ws, scale_ws);

    dim3 g2(DIM, BATCH);              // 12288 blocks
    gather_kernel<<<g2, dim3(256), 0, stream>>>(x, idx_ws, scale_ws, out);
}

// Round 4
// 380.170 us; speedup vs baseline: 1.2550x; 1.0130x over previous
//
#include <hip/hip_runtime.h>

// LengthRegulator: out[b,d,m] = x[b, d, idx[b,m]] * path[b, idx[b,m], m]
// (path one-hot along text axis, idx sorted along m).
//
//  K1: per mel column find the one-hot row. idx[m] is the m-th order stat of
//      4096 uniforms over [0,512) => idx[m] ~ m/8, sigma ~4 rows. Scan from
//      wave-uniform (m/8 - 24) (6+ sigma slack) in groups of 16 outstanding
//      loads; full rescan fallback guarantees correctness for any input.
//  K2: one block per (b, 8 d-rows): idx/scale read ONCE into registers,
//      8 x-rows staged in LDS, output streamed with nontemporal 16B stores.

#define BATCH   32
#define DIM     384
#define T_TEXT  512
#define T_MEL   4096
#define ROWS    8     // d-rows per block in K2

typedef float  nfloat4 __attribute__((ext_vector_type(4)));  // native vec for nontemporal builtin

__global__ __launch_bounds__(256) void find_idx_kernel(
    const float* __restrict__ path,    // [B, T_TEXT, T_MEL]
    int*   __restrict__ idx_ws,        // [B, T_MEL]
    float* __restrict__ scale_ws)      // [B, T_MEL]
{
    const int b = blockIdx.y;
    const int m = blockIdx.x * 256 + threadIdx.x;
    const float* pcol = path + (size_t)b * T_TEXT * T_MEL + m;

    int start = (m & ~63) / 8 - 24;    // wave-uniform, ~6 sigma below idx[m]
    if (start < 0) start = 0;

    int   idx   = 0;
    float scale = 0.0f;
    bool  found = false;

    for (int n = start; n < T_TEXT; n += 16) {
        float v[16];
        #pragma unroll
        for (int j = 0; j < 16; ++j) {
            const int row = n + j;
            v[j] = (row < T_TEXT) ? pcol[(size_t)row * T_MEL] : 0.0f;
        }
        #pragma unroll
        for (int j = 0; j < 16; ++j)
            if (v[j] != 0.0f) { idx = n + j; scale = v[j]; found = true; }
        if (__all(found)) break;       // idx sorted => wave's hits cluster
    }
    if (!__all(found)) {               // guaranteed-correct fallback
        for (int n = 0; n < T_TEXT; n += 16) {
            float v[16];
            #pragma unroll
            for (int j = 0; j < 16; ++j) {
                const int row = n + j;
                v[j] = (row < T_TEXT) ? pcol[(size_t)row * T_MEL] : 0.0f;
            }
            #pragma unroll
            for (int j = 0; j < 16; ++j)
                if (!found && v[j] != 0.0f) { idx = n + j; scale = v[j]; found = true; }
            if (__all(found)) break;
        }
    }
    idx_ws[b * T_MEL + m]   = idx;
    scale_ws[b * T_MEL + m] = scale;
}

__global__ __launch_bounds__(256) void gather_kernel(
    const float* __restrict__ x,        // [B, D, T_TEXT]
    const int*   __restrict__ idx_ws,   // [B, T_MEL]
    const float* __restrict__ scale_ws, // [B, T_MEL]
    float* __restrict__ out)            // [B, D, T_MEL]
{
    const int dg = blockIdx.x;          // d-group (8 rows)
    const int b  = blockIdx.y;
    const int t  = threadIdx.x;

    __shared__ float xs[ROWS * T_TEXT];         // 16 KB
    const float* xr = x + ((size_t)b * DIM + dg * ROWS) * T_TEXT;
    #pragma unroll
    for (int i = 0; i < ROWS * T_TEXT / 1024; ++i) {   // 4 float4 per thread
        const int off = i * 1024 + t * 4;
        *(nfloat4*)(xs + off) = *(const nfloat4*)(xr + off);
    }

    // idx/scale for this batch: read ONCE, kept in registers across all rows
    const int*   ip = idx_ws   + b * T_MEL;
    const float* sp = scale_ws + b * T_MEL;
    int4   i4[4];
    float4 s4[4];
    #pragma unroll
    for (int mt = 0; mt < 4; ++mt) {
        const int m4 = mt * 1024 + t * 4;
        i4[mt] = *(const int4*)  (ip + m4);
        s4[mt] = *(const float4*)(sp + m4);
    }
    __syncthreads();

    float* orow = out + ((size_t)b * DIM + dg * ROWS) * T_MEL;
    #pragma unroll
    for (int r = 0; r < ROWS; ++r) {
        const float* xsr = xs + r * T_TEXT;
        #pragma unroll
        for (int mt = 0; mt < 4; ++mt) {
            const int m4 = mt * 1024 + t * 4;
            nfloat4 o;
            o.x = xsr[i4[mt].x] * s4[mt].x;   // clustered idx -> LDS broadcast
            o.y = xsr[i4[mt].y] * s4[mt].y;
            o.z = xsr[i4[mt].z] * s4[mt].z;
            o.w = xsr[i4[mt].w] * s4[mt].w;
            __builtin_nontemporal_store(o, (nfloat4*)(orow + (size_t)r * T_MEL + m4));
        }
    }
}

extern "C" void kernel_launch(void* const* d_in, const int* in_sizes, int n_in,
                              void* d_out, int out_size, void* d_ws, size_t ws_size,
                              hipStream_t stream) {
    (void)in_sizes; (void)n_in; (void)ws_size; (void)out_size;
    const float* x    = (const float*)d_in[0];   // [32, 384, 512]
    const float* path = (const float*)d_in[1];   // [32, 512, 4096]
    float*       out  = (float*)d_out;           // [32, 384, 4096]

    int*   idx_ws   = (int*)d_ws;                          // 512 KB
    float* scale_ws = (float*)((char*)d_ws + (size_t)BATCH * T_MEL * sizeof(int));

    dim3 g1(T_MEL / 256, BATCH);          // 512 blocks
    find_idx_kernel<<<g1, dim3(256), 0, stream>>>(path, idx_ws, scale_ws);

    dim3 g2(DIM / ROWS, BATCH);           // 1536 blocks, 6/CU
    gather_kernel<<<g2, dim3(256), 0, stream>>>(x, idx_ws, scale_ws, out);
}